// Round 1
// baseline (100.201 us; speedup 1.0000x reference)
//
#include <hip/hip_runtime.h>

#define NUM_VARS    10000
#define NUM_CLAUSES 100000
#define BATCH       256

// Kernel 0: init d_out to +inf for the atomicMin pass (harness re-poisons
// d_out every call). Deliberately touches NOTHING else: this session's
// experiment is dropping ALL d_ws usage — the 256 MiB ws poison fills
// (41.7 us each, ~2 per timed call = 83 us) dominate the 91 us measurement,
// while our kernels sum to ~8 us.
__global__ __launch_bounds__(256) void fuzzy_init_out(float* __restrict__ out)
{
    out[threadIdx.x] = __uint_as_float(0x7F800000u);  // +inf
}

// Batch-quarter split with XCD steering: fp32 gather footprint per quarter
// is 10000 vars x 64 cols x 4 B = 2.56 MB < 4 MiB per-XCD L2 -> L2-resident.
// XCDs {0,1}->cols 0-63, {2,3}->64-127, {4,5}->128-191, {6,7}->192-255.
// One lane owns one fp32 column: a wave's gather = 64 x 4 B = 256 B, one
// coalesced transaction. Negation: neg ? 1-x : x == |x - n| exactly
// (x in [0,1), n in {0,1}) -> v_sub + abs-modifier folded into max3.
__global__ __launch_bounds__(512, 4) void fuzzy_cnf_fp32(
    const float* __restrict__ input,   // [NUM_VARS, BATCH] fp32
    const int*   __restrict__ lit_idx, // [NUM_CLAUSES, 3]
    const int*   __restrict__ lit_neg, // [NUM_CLAUSES, 3]
    float*       __restrict__ out)     // [BATCH]
{
    const int wave = threadIdx.x >> 6;              // 0..7
    const int lane = threadIdx.x & 63;
    const int xcd  = blockIdx.x & 7;                // round-robin heuristic
    const int quarter = xcd >> 1;                   // 2 XCDs per batch quarter
    const int qBlock  = ((blockIdx.x >> 3) << 1) | (xcd & 1);  // 0..255
    const int gwave   = qBlock * 8 + wave;          // 0..2047 within quarter
    const int total_waves = 2048;
    const int colBase = quarter * 64;

    float acc = 1e30f;

    #pragma unroll 4
    for (int c = gwave; c < NUM_CLAUSES; c += total_waves) {
        const int base = c * 3;
        // Wave-uniform clause metadata: force to SGPRs so the gather base
        // is scalar (global_load_dword v, v_laneoff, s[base]).
        const int i0 = __builtin_amdgcn_readfirstlane(lit_idx[base + 0]);
        const int i1 = __builtin_amdgcn_readfirstlane(lit_idx[base + 1]);
        const int i2 = __builtin_amdgcn_readfirstlane(lit_idx[base + 2]);
        const float n0 = (float)__builtin_amdgcn_readfirstlane(lit_neg[base + 0]);
        const float n1 = (float)__builtin_amdgcn_readfirstlane(lit_neg[base + 1]);
        const float n2 = (float)__builtin_amdgcn_readfirstlane(lit_neg[base + 2]);

        const float x0 = input[(i0 << 8) + colBase + lane];
        const float x1 = input[(i1 << 8) + colBase + lane];
        const float x2 = input[(i2 << 8) + colBase + lane];

        const float m = fmaxf(fmaxf(fabsf(x0 - n0), fabsf(x1 - n1)),
                              fabsf(x2 - n2));   // v_max3 with abs mods
        acc = fminf(acc, m);
    }

    // 8 waves -> 1 partial min per column in LDS (64 consecutive floats per
    // wave row: 2-way bank aliasing = free), then one device atomicMin per
    // column per block (values >= 0 so float-bit order == uint order).
    __shared__ float sm[8][64];
    sm[wave][lane] = acc;
    __syncthreads();

    if (threadIdx.x < 64) {
        float m = sm[0][threadIdx.x];
        #pragma unroll
        for (int w = 1; w < 8; ++w) m = fminf(m, sm[w][threadIdx.x]);
        atomicMin((unsigned int*)out + colBase + threadIdx.x, __float_as_uint(m));
    }
}

extern "C" void kernel_launch(void* const* d_in, const int* in_sizes, int n_in,
                              void* d_out, int out_size, void* d_ws, size_t ws_size,
                              hipStream_t stream) {
    const float* input   = (const float*)d_in[0];
    const int*   lit_idx = (const int*)d_in[1];
    const int*   lit_neg = (const int*)d_in[2];
    float*       out     = (float*)d_out;

    (void)d_ws; (void)ws_size;  // intentionally unused — see theory note

    fuzzy_init_out<<<1, 256, 0, stream>>>(out);
    fuzzy_cnf_fp32<<<1024, 512, 0, stream>>>(input, lit_idx, lit_neg, out);
}

// Round 2
// 78.310 us; speedup vs baseline: 1.2795x; 1.2795x over previous
//
#include <hip/hip_runtime.h>

#define NUM_VARS    10000
#define NUM_CLAUSES 100000
#define BATCH       256
#define CPI         8                     // clauses per chunk
#define NCHUNK      (NUM_CLAUSES / CPI)   // 12500 exact
#define WAVES_Q     2048                  // waves per batch-quarter

// Batch-quarter split with XCD steering: fp32 gather footprint per quarter
// is 10000 x 64 x 4 B = 2.56 MB < 4 MiB per-XCD L2 -> L2-resident.
// XCD pair {2q,2q+1} owns batch columns [64q, 64q+64).
//
// ILP restructure vs round 1 (which was latency-serialized at VGPR=12):
//  - gwave is readfirstlane-uniform -> clause metadata reads compile to
//    s_load_dwordx16/x8 (contiguous 96 B per chunk), issued ahead on lgkmcnt.
//  - all 24 gathers of an 8-clause chunk issue into explicit regs before any
//    use: 24 in-flight L2 loads/wave x 8 waves/SIMD >> 300-cyc L2 latency.
//  - negation: neg ? 1-x : x == |x - n| exactly (x in [0,1), n in {0,1});
//    nested fmaxf(fabsf...) folds to v_max3_f32 with abs input modifiers.
__global__ __launch_bounds__(512, 8) void fuzzy_cnf_fp32(
    const float* __restrict__ input,   // [NUM_VARS, BATCH] fp32
    const int*   __restrict__ lit_idx, // [NUM_CLAUSES, 3]
    const int*   __restrict__ lit_neg, // [NUM_CLAUSES, 3]
    float*       __restrict__ out)     // [BATCH]
{
    const int wave = threadIdx.x >> 6;              // 0..7
    const int lane = threadIdx.x & 63;
    const int xcd  = blockIdx.x & 7;                // round-robin heuristic
    const int quarter = xcd >> 1;                   // 2 XCDs per batch quarter
    const int qBlock  = ((blockIdx.x >> 3) << 1) | (xcd & 1);   // 0..127
    const int gwave   = __builtin_amdgcn_readfirstlane(qBlock * 8 + wave); // 0..2047
    const int colBase = quarter * 64;
    const int coff    = colBase + lane;             // per-lane column (VGPR)

    float acc = 1e30f;

    #pragma unroll 1   // keep one chunk's state live: ~40 VGPR, 8 waves/SIMD
    for (int ch = gwave; ch < NCHUNK; ch += WAVES_Q) {
        const int base = ch * (CPI * 3);            // SGPR

        int   idx[CPI * 3];
        float nf [CPI * 3];
        #pragma unroll
        for (int j = 0; j < CPI * 3; ++j) idx[j] = lit_idx[base + j];   // s_load
        #pragma unroll
        for (int j = 0; j < CPI * 3; ++j) nf[j] = lit_neg[base + j] ? 1.0f : 0.0f;

        float x[CPI * 3];
        #pragma unroll
        for (int j = 0; j < CPI * 3; ++j)
            x[j] = input[(idx[j] << 8) + coff];     // saddr-form gather, 256B/wave

        #pragma unroll
        for (int q = 0; q < CPI; ++q) {
            const float m = fmaxf(fmaxf(fabsf(x[3*q+0] - nf[3*q+0]),
                                        fabsf(x[3*q+1] - nf[3*q+1])),
                                  fabsf(x[3*q+2] - nf[3*q+2]));
            acc = fminf(acc, m);
        }
    }

    // 8 waves -> 1 partial min per column in LDS, then one device atomicMin
    // per column per block (values >= 0 so float-bit order == uint order).
    __shared__ float sm[8][64];
    sm[wave][lane] = acc;
    __syncthreads();

    if (threadIdx.x < 64) {
        float m = sm[0][threadIdx.x];
        #pragma unroll
        for (int w = 1; w < 8; ++w) m = fminf(m, sm[w][threadIdx.x]);
        atomicMin((unsigned int*)out + colBase + threadIdx.x, __float_as_uint(m));
    }
}

extern "C" void kernel_launch(void* const* d_in, const int* in_sizes, int n_in,
                              void* d_out, int out_size, void* d_ws, size_t ws_size,
                              hipStream_t stream) {
    const float* input   = (const float*)d_in[0];
    const int*   lit_idx = (const int*)d_in[1];
    const int*   lit_neg = (const int*)d_in[2];
    float*       out     = (float*)d_out;

    (void)d_ws; (void)ws_size;  // still unused: isolates the ILP experiment

    // Init out to 0x7F7F7F7F (3.39e38): larger (in float AND uint order) than
    // any result, so it can't survive the atomicMin pass. Replaces the init
    // kernel launch; memset-on-stream is graph-capturable.
    hipMemsetAsync(out, 0x7F, BATCH * sizeof(float), stream);

    fuzzy_cnf_fp32<<<1024, 512, 0, stream>>>(input, lit_idx, lit_neg, out);
}